// Round 17
// baseline (165.177 us; speedup 1.0000x reference)
//
#include <hip/hip_runtime.h>
#include <math.h>

// B=8, C=128, N=4096, d=16, groups=32
// R17 = R15/R16 attn (VERBATIM) + GN folded into gnprep.
//   gnprep now: stats per (b,g) -> broadcast mu/rs in-block -> write
//   normalized bf16 x in MFMA-B-frag tiled layout XG[b][n>>4][c>>3][n&15][c&7]
//   (8 uint2 stores/thread). qkv becomes a pure GEMM: 8 direct b128 B-frag
//   loads from XG (L2-hot, same XCD) + wcatb A-frags + MFMA + stores.
//   No x loads, no GN math, no LDS staging, no barrier in qkv.
// Rationale: qkv invariant at ~55 us across two different inner loops;
//   the shared front-end (16-deep scalar x-load + GN + pack chain) is the
//   suspected latency sink. This removes it entirely.

typedef short v8s __attribute__((ext_vector_type(8)));   // 8 bf16 = 4 VGPRs
typedef float v16f __attribute__((ext_vector_type(16))); // 32x32 acc

__device__ __forceinline__ unsigned short f2bf_rne(float f) {
  unsigned u = __float_as_uint(f);
  u += 0x7fffu + ((u >> 16) & 1u);
  return (unsigned short)(u >> 16);
}

__device__ __forceinline__ v8s mk8(unsigned a, unsigned b, unsigned c, unsigned d) {
  union { unsigned u[4]; v8s s; } x;
  x.u[0] = a; x.u[1] = b; x.u[2] = c; x.u[3] = d;
  return x.s;
}

// pack two fp32 -> dword of 2 bf16 (truncation) in ONE v_perm_b32
__device__ __forceinline__ unsigned pack_trunc(float hi, float lo) {
  return __builtin_amdgcn_perm(__float_as_uint(hi), __float_as_uint(lo), 0x07060302u);
}

// tiled V element index: [b][j>>4][c][j&15]
#define VT(b, n, c) (((((size_t)(b) * 256 + ((n) >> 4)) << 7) + (c)) * 16 + ((n) & 15))
// tiled normalized-x (B-frag) index: [b][n>>4][c>>3][n&15][c&7]
#define XG(b, n, c) (((size_t)((b) * 256 + ((n) >> 4)) * 2048) + ((((c) >> 3)) << 7) + (((n) & 15) << 3) + ((c) & 7))

// ws byte offsets
#define WSB_WCATB  4096u       // 160*128 bf16 = 40960
#define WSB_BCAT   49152u      // 160 f32
#define WSB_PWB    65536u      // 128*128 bf16 = 32768
#define WSB_QBF    131072u     // Q^T [B,16,N] bf16 = 1 MB
#define WSB_KBF    1310720u    // K [B,N,16] bf16 = 1 MB
#define WSB_VBF    2621440u    // 8 MB (tiled)
#define WSB_XGN    11010048u   // 8 MB (tiled normalized x, bf16)

// ---------------------------------------------------------------------------
// gnprep: weights prep + GN stats + normalized bf16 x in XG layout.
// Grid 256 x 512 thr; block = (b = id&7, g = id>>3) -> XCD-pinned.
// ---------------------------------------------------------------------------
__global__ __launch_bounds__(512)
void gnprep_kernel(const float* __restrict__ x,
                   const float* __restrict__ gnw, const float* __restrict__ gnb,
                   const float* __restrict__ qw, const float* __restrict__ qb,
                   const float* __restrict__ kw, const float* __restrict__ kb,
                   const float* __restrict__ vw, const float* __restrict__ vb,
                   const float* __restrict__ pw,
                   unsigned short* __restrict__ wcatb, float* __restrict__ bcat,
                   unsigned short* __restrict__ pwb,
                   unsigned short* __restrict__ xgn) {
  const int id = blockIdx.x;
  // ---- prep part ----
  {
    const float qs = 0.36067376022224085f;  // 0.25 * log2(e)
    int idx = id * 512 + threadIdx.x;
    if (idx < 160 * 128) {
      int o = idx >> 7, c = idx & 127;
      float val;
      if (o < 16)       val = qw[o * 128 + c] * qs;
      else if (o < 32)  val = kw[(o - 16) * 128 + c];
      else              val = vw[(o - 32) * 128 + c];
      wcatb[idx] = f2bf_rne(val);
    } else if (idx < 160 * 128 + 160) {
      int o = idx - 160 * 128;
      bcat[o] = (o < 16) ? qb[o] * qs : (o < 32) ? kb[o - 16] : vb[o - 32];
    } else if (idx < 160 * 128 + 160 + 128 * 128) {
      int j = idx - (160 * 128 + 160);
      pwb[j] = f2bf_rne(pw[j]);
    }
  }
  // ---- gn stats (x held in regs) ----
  const int b = id & 7, g = id >> 3;
  const int bg = b * 32 + g;
  const float4* xp = (const float4*)(x + (size_t)bg * 16384);
  float4 xv[8];
  float s = 0.f, ss = 0.f;
#pragma unroll
  for (int u = 0; u < 8; ++u) {
    xv[u] = xp[threadIdx.x + u * 512];
    s  += xv[u].x + xv[u].y + xv[u].z + xv[u].w;
    ss += xv[u].x * xv[u].x + xv[u].y * xv[u].y
        + xv[u].z * xv[u].z + xv[u].w * xv[u].w;
  }
  for (int off = 32; off > 0; off >>= 1) {
    s  += __shfl_down(s, off, 64);
    ss += __shfl_down(ss, off, 64);
  }
  __shared__ float red[16];
  __shared__ float musr[2];
  int lane = threadIdx.x & 63, wid = threadIdx.x >> 6;
  if (lane == 0) { red[wid * 2] = s; red[wid * 2 + 1] = ss; }
  __syncthreads();
  if (threadIdx.x == 0) {
    float S = 0.f, SS = 0.f;
    for (int w2 = 0; w2 < 8; ++w2) { S += red[w2 * 2]; SS += red[w2 * 2 + 1]; }
    float mu  = S * (1.0f / 16384.0f);
    float var = SS * (1.0f / 16384.0f) - mu * mu;
    musr[0] = mu;
    musr[1] = rsqrtf(var + 1e-5f);
  }
  __syncthreads();
  const float mu = musr[0], rs = musr[1];
  // per-thread scale/shift for this block's 4 channels
  float sc[4], sh[4];
#pragma unroll
  for (int cl = 0; cl < 4; ++cl) {
    int c = 4 * g + cl;
    sc[cl] = rs * gnw[c];
    sh[cl] = gnb[c] - mu * sc[cl];
  }
  // write normalized bf16 x to XG: xv[u] (u<2) pairs with xv[u+2,4,6]
  // (same n, channels 4g..4g+3) -> uint2 of 4 bf16 per (u,k).
#pragma unroll
  for (int u = 0; u < 2; ++u) {
    const int n0 = (threadIdx.x + u * 512) * 4;
    const float* f0 = (const float*)&xv[u];
    const float* f1 = (const float*)&xv[u + 2];
    const float* f2 = (const float*)&xv[u + 4];
    const float* f3 = (const float*)&xv[u + 6];
#pragma unroll
    for (int k = 0; k < 4; ++k) {
      const int n = n0 + k;
      unsigned e0 = f2bf_rne(f0[k] * sc[0] + sh[0]);
      unsigned e1 = f2bf_rne(f1[k] * sc[1] + sh[1]);
      unsigned e2 = f2bf_rne(f2[k] * sc[2] + sh[2]);
      unsigned e3 = f2bf_rne(f3[k] * sc[3] + sh[3]);
      uint2 uu; uu.x = e0 | (e1 << 16); uu.y = e2 | (e3 << 16);
      *(uint2*)(xgn + XG(b, n, 4 * g)) = uu;
    }
  }
}

// ---------------------------------------------------------------------------
// R17 QKV: pure GEMM. 8 direct b128 B-frag loads from XG + wcatb A-frags.
// Block 512 thr (8 waves), n-tile 64, grid 512, XCD-pinned. No LDS staging.
// ---------------------------------------------------------------------------
__global__ __launch_bounds__(512)
void qkv_kernel(const unsigned short* __restrict__ xgn,
                const unsigned short* __restrict__ wcatb, const float* __restrict__ bcat,
                unsigned short* __restrict__ qTb, unsigned short* __restrict__ kbf,
                unsigned short* __restrict__ vbf) {
  __shared__ float bsh[160];
  const int id = blockIdx.x;
  const int b = id & 7, nb = (id >> 3) << 6;   // XCD-pinned batch
  const int t = threadIdx.x;
  const int w = t >> 6, lane = t & 63, h = lane >> 5, l = lane & 31;
  const int nsub = w & 1, og = w >> 1;
  if (t < 160) bsh[t] = bcat[t];
  __syncthreads();

  const int n = nb + nsub * 32 + l;
  const int otbase = (og == 0) ? 0 : og + 1;

  // B-frags direct from XG (coalesced 256B runs, L2-hot from gnprep)
  const size_t xbase = (size_t)(b * 256 + (n >> 4)) * 2048 + ((n & 15) << 3);
  v8s bf[8];
#pragma unroll
  for (int ks = 0; ks < 8; ++ks)
    bf[ks] = *(const v8s*)(xgn + xbase + ((ks * 2 + h) << 7));

  v16f acc[2];
#pragma unroll
  for (int a2 = 0; a2 < 2; ++a2)
#pragma unroll
    for (int r = 0; r < 16; ++r) acc[a2][r] = 0.f;

#pragma unroll
  for (int ks = 0; ks < 8; ++ks) {
    {
      v8s af = *(const v8s*)(wcatb + (otbase * 32 + l) * 128 + ks * 16 + 8 * h);
      acc[0] = __builtin_amdgcn_mfma_f32_32x32x16_bf16(af, bf[ks], acc[0], 0, 0, 0);
    }
    if (og == 0) {
      v8s af = *(const v8s*)(wcatb + (32 + l) * 128 + ks * 16 + 8 * h);
      acc[1] = __builtin_amdgcn_mfma_f32_32x32x16_bf16(af, bf[ks], acc[1], 0, 0, 0);
    }
  }

  // ---- epilogue (unchanged) ----
  if (og == 0) {
    const size_t nqk = ((size_t)b * 4096 + n) << 4;
#pragma unroll
    for (int r = 0; r < 16; ++r) {
      int o = 4 * h + (r & 3) + 8 * (r >> 2);
      unsigned short bv = f2bf_rne(acc[0][r] + bsh[o]);
      if (o < 16) qTb[((size_t)(b * 16 + o) << 12) + n] = bv;
      else        kbf[nqk + o - 16] = bv;
    }
#pragma unroll
    for (int r = 0; r < 16; ++r) {
      int o = 32 + 4 * h + (r & 3) + 8 * (r >> 2);
      vbf[VT(b, n, o - 32)] = f2bf_rne(acc[1][r] + bsh[o]);
    }
  } else {
#pragma unroll
    for (int r = 0; r < 16; ++r) {
      int o = otbase * 32 + 4 * h + (r & 3) + 8 * (r >> 2);
      vbf[VT(b, n, o - 32)] = f2bf_rne(acc[0][r] + bsh[o]);
    }
  }
}

// ---------------------------------------------------------------------------
// R15 flash attention + fused proj (VERBATIM).
// ---------------------------------------------------------------------------
#define VS 24                     // shorts per V row (16 data + 8 pad)
#define OTS 136                   // O^T row stride in shorts (68 dwords)

__global__ __launch_bounds__(256)
void attn_kernel(const unsigned short* __restrict__ qTb,
                 const unsigned short* __restrict__ kbf,
                 const unsigned short* __restrict__ vbf,
                 const unsigned short* __restrict__ pwb,
                 const float* __restrict__ pb,
                 const float* __restrict__ x,
                 float* __restrict__ out) {
  __shared__ alignas(16) unsigned short smem[2][512 * VS];   // 49152 B
  __shared__ float l_lds[64];
  __shared__ float pbs[128];

  const int id = blockIdx.x;
  const int b = id & 7, i0 = (id >> 3) << 6;   // XCD-pinned batch, 64-i tile
  const int t = threadIdx.x;
  const int w = t >> 6, lane = t & 63, h = lane >> 5, l = lane & 31;
  const int jsub = w & 1, ihalf = w >> 1;

  const unsigned short* kg = kbf + ((size_t)b << 16);
  const unsigned short* vg = vbf + ((size_t)b << 19);

  if (t < 128) pbs[t] = pb[t];

  // Q B-frag from Q^T [B,16,N]: 8 coalesced b16 loads, once per kernel
  const int iglob = i0 + ihalf * 32 + l;
  unsigned qd[4];
#pragma unroll
  for (int e = 0; e < 4; ++e) {
    unsigned lo = qTb[((size_t)(b * 16 + 8 * h + 2 * e) << 12) + iglob];
    unsigned hi = qTb[((size_t)(b * 16 + 8 * h + 2 * e + 1) << 12) + iglob];
    qd[e] = lo | (hi << 16);
  }
  const v8s qf = mk8(qd[0], qd[1], qd[2], qd[3]);

  v16f zc;
#pragma unroll
  for (int r = 0; r < 16; ++r) zc[r] = 0.f;
  v16f acc[4];
#pragma unroll
  for (int ct = 0; ct < 4; ++ct)
#pragma unroll
    for (int r = 0; r < 16; ++r) acc[ct][r] = 0.f;
  float ls = 0.f;

  // staging: per thread 4 chunks: rows w*128 + (lane>>1) + {0,32,64,96}
  const int srow = w * 128 + (lane >> 1);
  const int sh16 = (lane & 1) * 8;

  // prologue: stage tile 0 into buf 0
#pragma unroll
  for (int u = 0; u < 4; ++u) {
    v8s a = *(const v8s*)(vg + (size_t)(srow + 32 * u) * 16 + sh16);
    *(v8s*)(&smem[0][(srow + 32 * u) * VS + sh16]) = a;
  }
  if (t < 64) l_lds[t] = 0.f;
  __syncthreads();

  for (int tile = 0; tile < 64; ++tile) {
    const int tn = (tile + 1) & 63;   // wrap: harmless reload on last iter
    unsigned short* const cur = smem[tile & 1];
    unsigned short* const nxt = smem[(tile + 1) & 1];

    // prefetch next V tile into regs (coalesced 2KB per wave-instr)
    v8s s[4];
#pragma unroll
    for (int u = 0; u < 4; ++u)
      s[u] = *(const v8s*)(vg + (size_t)tn * 8192 + (size_t)(srow + 32 * u) * 16 + sh16);

    // K A-frag direct from global (coalesced 1KB)
    v8s kf = *(const v8s*)(kg + (((size_t)(tile * 64 + jsub * 32 + l)) << 4) + 8 * h);

    // QK: S^T patch (rows j, cols i) -> P in regs
    v16f st = __builtin_amdgcn_mfma_f32_32x32x16_bf16(kf, qf, zc, 0, 0, 0);
    float pe[16];
#pragma unroll
    for (int r = 0; r < 16; ++r) { pe[r] = __builtin_amdgcn_exp2f(st[r]); ls += pe[r]; }
    unsigned G[8];
#pragma unroll
    for (int g = 0; g < 4; ++g) {
      G[2 * g]     = pack_trunc(pe[4 * g + 1], pe[4 * g]);
      G[2 * g + 1] = pack_trunc(pe[4 * g + 3], pe[4 * g + 2]);
    }
    // half-wave exchange (proven mapping): 4 shfl + selects
    unsigned S0 = h ? G[0] : G[2], S1 = h ? G[1] : G[3];
    unsigned S2 = h ? G[4] : G[6], S3 = h ? G[5] : G[7];
    unsigned R0 = (unsigned)__shfl_xor((int)S0, 32, 64);
    unsigned R1 = (unsigned)__shfl_xor((int)S1, 32, 64);
    unsigned R2 = (unsigned)__shfl_xor((int)S2, 32, 64);
    unsigned R3 = (unsigned)__shfl_xor((int)S3, 32, 64);
    v8s pf0 = h ? mk8(R0, R1, G[2], G[3]) : mk8(G[0], G[1], R0, R1);
    v8s pf1 = h ? mk8(R2, R3, G[6], G[7]) : mk8(G[4], G[5], R2, R3);

    // PV from cur (conflict-free b128 reads)
#pragma unroll
    for (int ct = 0; ct < 4; ++ct) {
      v8s vf0 = *(const v8s*)(&cur[((jsub * 2) * 128 + ct * 32 + l) * VS + 8 * h]);
      v8s vf1 = *(const v8s*)(&cur[((jsub * 2 + 1) * 128 + ct * 32 + l) * VS + 8 * h]);
      acc[ct] = __builtin_amdgcn_mfma_f32_32x32x16_bf16(vf0, pf0, acc[ct], 0, 0, 0);
      acc[ct] = __builtin_amdgcn_mfma_f32_32x32x16_bf16(vf1, pf1, acc[ct], 0, 0, 0);
    }

    // commit prefetched tile to nxt (no reader until after barrier)
#pragma unroll
    for (int u = 0; u < 4; ++u)
      *(v8s*)(&nxt[(srow + 32 * u) * VS + sh16]) = s[u];

    __syncthreads();
  }

  // ---- epilogue: jsub combine, then fused proj ----
  atomicAdd(&l_lds[ihalf * 32 + l], ls);
  __syncthreads();   // all PV reads done; V buffers dead; l complete

  float* const ov = (float*)smem;   // f32 combine overlay
  if (jsub == 1) {
#pragma unroll
    for (int ct = 0; ct < 4; ++ct)
#pragma unroll
      for (int q = 0; q < 4; ++q) {
        float4 v4 = {acc[ct][4 * q], acc[ct][4 * q + 1],
                     acc[ct][4 * q + 2], acc[ct][4 * q + 3]};
        *(float4*)&ov[((ct * 2 + ihalf) * 32 + l) * 36 + 4 * h + 8 * q] = v4;
      }
  }
  __syncthreads();
  if (jsub == 0) {
#pragma unroll
    for (int ct = 0; ct < 4; ++ct)
#pragma unroll
      for (int q = 0; q < 4; ++q) {
        float4 v4 = *(float4*)&ov[((ct * 2 + ihalf) * 32 + l) * 36 + 4 * h + 8 * q];
        acc[ct][4 * q]     += v4.x;
        acc[ct][4 * q + 1] += v4.y;
        acc[ct][4 * q + 2] += v4.z;
        acc[ct][4 * q + 3] += v4.w;
      }
  }
  __syncthreads();   // ov reads complete; smem reusable

  // jsub=0 waves write normalized O^T bf16 [n_local][c], stride OTS
  unsigned short* const oT = (unsigned short*)smem;
  if (jsub == 0) {
    const float li = 1.f / l_lds[ihalf * 32 + l];
    const int nrow = ihalf * 32 + l;
#pragma unroll
    for (int ct = 0; ct < 4; ++ct)
#pragma unroll
      for (int r = 0; r < 16; r += 2) {
        int c = ct * 32 + 4 * h + (r & 3) + 8 * (r >> 2);   // even
        unsigned dw = (unsigned)f2bf_rne(acc[ct][r] * li) |
                      ((unsigned)f2bf_rne(acc[ct][r + 1] * li) << 16);
        *(unsigned*)(&oT[nrow * OTS + c]) = dw;
      }
  }
  __syncthreads();

  // fused proj: wave w -> e-tile w (32 e), both n-subs. out = pw@O + pb + x.
#pragma unroll
  for (int nsub = 0; nsub < 2; ++nsub) {
    v16f a2;
#pragma unroll
    for (int r = 0; r < 16; ++r) a2[r] = 0.f;
#pragma unroll
    for (int ks = 0; ks < 8; ++ks) {
      v8s bf = *(const v8s*)(&oT[(nsub * 32 + l) * OTS + ks * 16 + 8 * h]);
      v8s af = *(const v8s*)(pwb + (w * 32 + l) * 128 + ks * 16 + 8 * h);
      a2 = __builtin_amdgcn_mfma_f32_32x32x16_bf16(af, bf, a2, 0, 0, 0);
    }
    const int n = i0 + nsub * 32 + l;
#pragma unroll
    for (int r = 0; r < 16; ++r) {
      int e = w * 32 + 4 * h + (r & 3) + 8 * (r >> 2);
      size_t idx = ((size_t)(b * 128 + e) << 12) + n;
      out[idx] = a2[r] + pbs[e] + x[idx];
    }
  }
}

// ---------------------------------------------------------------------------
extern "C" void kernel_launch(void* const* d_in, const int* in_sizes, int n_in,
                              void* d_out, int out_size, void* d_ws, size_t ws_size,
                              hipStream_t stream) {
  const float* x   = (const float*)d_in[0];
  const float* gnw = (const float*)d_in[1];
  const float* gnb = (const float*)d_in[2];
  const float* qw  = (const float*)d_in[3];
  const float* qb  = (const float*)d_in[4];
  const float* kw  = (const float*)d_in[5];
  const float* kb  = (const float*)d_in[6];
  const float* vw  = (const float*)d_in[7];
  const float* vb  = (const float*)d_in[8];
  const float* pw  = (const float*)d_in[9];
  const float* pb  = (const float*)d_in[10];
  float* out = (float*)d_out;
  char* ws = (char*)d_ws;

  unsigned short* wcatb = (unsigned short*)(ws + WSB_WCATB);
  float* bcat = (float*)(ws + WSB_BCAT);
  unsigned short* pwb = (unsigned short*)(ws + WSB_PWB);
  unsigned short* qTb = (unsigned short*)(ws + WSB_QBF);
  unsigned short* kbf = (unsigned short*)(ws + WSB_KBF);
  unsigned short* vbf = (unsigned short*)(ws + WSB_VBF);
  unsigned short* xgn = (unsigned short*)(ws + WSB_XGN);

  hipLaunchKernelGGL(gnprep_kernel, dim3(256), dim3(512), 0, stream,
                     x, gnw, gnb, qw, qb, kw, kb, vw, vb, pw, wcatb, bcat, pwb, xgn);
  hipLaunchKernelGGL(qkv_kernel, dim3(512), dim3(512), 0, stream,
                     xgn, wcatb, bcat, qTb, kbf, vbf);
  hipLaunchKernelGGL(attn_kernel, dim3(512), dim3(256), 0, stream,
                     qTb, kbf, vbf, pwb, pb, x, out);
}